// Round 1
// baseline (1099.606 us; speedup 1.0000x reference)
//
#include <hip/hip_runtime.h>
#include <hip/hip_bf16.h>
#include <cstdint>

#define CDIV(a,b) (((a)+(b)-1)/(b))

__device__ __forceinline__ float lrelu(float x){ return x > 0.f ? x : 0.2f*x; }
__device__ __forceinline__ float eluf(float x){ return x > 0.f ? x : __expf(x) - 1.f; }

// ---------------- CSR build (by dst) ----------------
__global__ void hist_k(const int* __restrict__ ei, int* __restrict__ deg, int ne, int etot){
  int e = blockIdx.x*256 + threadIdx.x;
  if (e >= etot) return;
  int d = (e < ne) ? ei[ne + e] : (e - ne);
  atomicAdd(&deg[d], 1);
}

constexpr int SCHUNK = 2048;

__global__ __launch_bounds__(256) void scan_part_k(const int* __restrict__ in, int* __restrict__ out,
                                                   int* __restrict__ blksum, int n){
  __shared__ int lds[256];
  int base = blockIdx.x*SCHUNK + threadIdx.x*8;
  int v[8]; int tsum = 0;
  #pragma unroll
  for (int k=0;k<8;k++){ int idx=base+k; int x=(idx<n)?in[idx]:0; v[k]=tsum; tsum+=x; }
  lds[threadIdx.x]=tsum; __syncthreads();
  for (int off=1; off<256; off<<=1){
    int y = (threadIdx.x>= (unsigned)off)? lds[threadIdx.x-off]:0;
    __syncthreads();
    lds[threadIdx.x]+=y;
    __syncthreads();
  }
  int excl = lds[threadIdx.x] - tsum;
  #pragma unroll
  for (int k=0;k<8;k++){ int idx=base+k; if(idx<n) out[idx]=excl+v[k]; }
  if (threadIdx.x==255) blksum[blockIdx.x]=lds[255];
}

__global__ __launch_bounds__(256) void scan_top_k(int* __restrict__ blksum, int nb){
  __shared__ int lds[256];
  int x = ((int)threadIdx.x<nb)? blksum[threadIdx.x]:0;
  lds[threadIdx.x]=x; __syncthreads();
  for (int off=1; off<256; off<<=1){
    int y=(threadIdx.x>=(unsigned)off)?lds[threadIdx.x-off]:0;
    __syncthreads();
    lds[threadIdx.x]+=y;
    __syncthreads();
  }
  if ((int)threadIdx.x<nb) blksum[threadIdx.x]=lds[threadIdx.x]-x;
}

__global__ void scan_add_k(int* __restrict__ rowstart, const int* __restrict__ blksum,
                           int* __restrict__ cursor, int n, int etot){
  int i = blockIdx.x*256+threadIdx.x;
  if (i<n){ int r = rowstart[i]+blksum[i/SCHUNK]; rowstart[i]=r; cursor[i]=r; }
  if (i==0) rowstart[n]=etot;
}

__global__ void scatter_k(const int* __restrict__ ei, int* __restrict__ cursor,
                          int* __restrict__ edge_src, int ne, int etot){
  int e = blockIdx.x*256+threadIdx.x;
  if (e>=etot) return;
  int s,d;
  if (e<ne){ s=ei[e]; d=ei[ne+e]; } else { s=e-ne; d=s; }
  int p = atomicAdd(&cursor[d],1);
  edge_src[p]=s;
}

// ---------------- GEMM + fused attention logits ----------------
// h = X @ W  (X: [n,K], W: [K,M], M = H*32), plus asrc/adst = einsum(h, att)
template<int K, int M, int H, int NPB>
__global__ __launch_bounds__(256) void gemm_att_k(const float* __restrict__ X, const float* __restrict__ W,
    const float* __restrict__ attS, const float* __restrict__ attD,
    float* __restrict__ Hout, float* __restrict__ asrc, float* __restrict__ adst, int n){
  constexpr int CG = M/4;          // col-groups of 4 cols
  constexpr int P  = 256/CG;       // nodes in flight per iteration
  __shared__ float Wl[K*M];
  __shared__ float Xl[P*K];
  for (int i = threadIdx.x; i < K*M; i += 256) Wl[i] = W[i];
  const int cg  = threadIdx.x % CG;
  const int sub = threadIdx.x / CG;
  const int nodeBase = blockIdx.x * NPB;
  for (int t0 = 0; t0 < NPB; t0 += P){
    __syncthreads();
    for (int i = threadIdx.x; i < P*K; i += 256){
      int nn = nodeBase + t0 + i/K;
      Xl[i] = (nn < n) ? X[(nodeBase+t0)*K + i] : 0.f;
    }
    __syncthreads();
    float a0=0.f,a1=0.f,a2=0.f,a3=0.f;
    #pragma unroll 4
    for (int k=0;k<K;++k){
      float4 w = *(const float4*)&Wl[k*M + cg*4];
      float xv = Xl[sub*K + k];
      a0 += xv*w.x; a1 += xv*w.y; a2 += xv*w.z; a3 += xv*w.w;
    }
    int c0 = cg*4;
    float vs = a0*attS[c0]+a1*attS[c0+1]+a2*attS[c0+2]+a3*attS[c0+3];
    float vd = a0*attD[c0]+a1*attD[c0+1]+a2*attD[c0+2]+a3*attD[c0+3];
    #pragma unroll
    for (int mask=1; mask<8; mask<<=1){ vs+=__shfl_xor(vs,mask); vd+=__shfl_xor(vd,mask); }
    int node = nodeBase + t0 + sub;
    if (node < n){
      *(float4*)&Hout[node*M + c0] = make_float4(a0,a1,a2,a3);
      if ((cg & 7)==0){
        int head = cg>>3;    // 8 col-groups (32 cols) per head
        asrc[node*H+head]=vs;
        adst[node*H+head]=vd;
      }
    }
  }
}

// ---------------- per-dst-node softmax + aggregation (one wave per node) ----------------
template<int H>
__global__ __launch_bounds__(256) void agg_k(const float* __restrict__ Hf, const float* __restrict__ asrc,
    const float* __restrict__ adst, const int* __restrict__ rowstart, const int* __restrict__ esrc,
    float* __restrict__ out, int n){
  int wid  = (int)((blockIdx.x*256 + threadIdx.x) >> 6);
  int lane = threadIdx.x & 63;
  if (wid >= n) return;
  int rs = rowstart[wid], re = rowstart[wid+1];

  float adl[H];
  #pragma unroll
  for (int h=0; h<H; ++h) adl[h] = adst[wid*H + h];

  // phase 1: segment max (wave-parallel over edges)
  float m[H];
  #pragma unroll
  for (int h=0; h<H; ++h) m[h] = -1e30f;
  for (int i = rs + lane; i < re; i += 64){
    int s = esrc[i];
    if constexpr (H==4){
      float4 a4 = *(const float4*)&asrc[s*4];
      m[0]=fmaxf(m[0], lrelu(a4.x+adl[0]));
      m[1]=fmaxf(m[1], lrelu(a4.y+adl[1]));
      m[2]=fmaxf(m[2], lrelu(a4.z+adl[2]));
      m[3]=fmaxf(m[3], lrelu(a4.w+adl[3]));
    } else {
      m[0]=fmaxf(m[0], lrelu(asrc[s]+adl[0]));
    }
  }
  #pragma unroll
  for (int h=0; h<H; ++h){
    #pragma unroll
    for (int mask=32; mask; mask>>=1) m[h] = fmaxf(m[h], __shfl_xor(m[h], mask));
  }

  // phase 2: segment sum of exp
  float sum[H];
  #pragma unroll
  for (int h=0; h<H; ++h) sum[h]=0.f;
  for (int i = rs + lane; i < re; i += 64){
    int s = esrc[i];
    if constexpr (H==4){
      float4 a4 = *(const float4*)&asrc[s*4];
      sum[0]+=__expf(lrelu(a4.x+adl[0])-m[0]);
      sum[1]+=__expf(lrelu(a4.y+adl[1])-m[1]);
      sum[2]+=__expf(lrelu(a4.z+adl[2])-m[2]);
      sum[3]+=__expf(lrelu(a4.w+adl[3])-m[3]);
    } else {
      sum[0]+=__expf(lrelu(asrc[s]+adl[0])-m[0]);
    }
  }
  #pragma unroll
  for (int h=0; h<H; ++h){
    #pragma unroll
    for (int mask=32; mask; mask>>=1) sum[h]+=__shfl_xor(sum[h],mask);
  }

  // phase 3: out[dst] = sum_e alpha_e * h[src_e]
  if constexpr (H==4){
    float iv0s = 1.f/sum[0], iv1s=1.f/sum[1], iv2s=1.f/sum[2], iv3s=1.f/sum[3];
    bool hi = (lane & 32) != 0;
    float ad0 = hi? adl[1]:adl[0], ad1 = hi? adl[3]:adl[2];
    float mm0 = hi? m[1]:m[0],     mm1 = hi? m[3]:m[2];
    float iv0 = hi? iv1s:iv0s,     iv1 = hi? iv3s:iv2s;
    int hsel = lane>>5;
    float acc0=0.f, acc1=0.f;
    for (int i=rs;i<re;++i){
      int s = esrc[i];
      float as0 = asrc[s*4+hsel], as1 = asrc[s*4+2+hsel];
      float a0 = __expf(lrelu(as0+ad0)-mm0)*iv0;
      float a1 = __expf(lrelu(as1+ad1)-mm1)*iv1;
      acc0 += a0*Hf[s*128+lane];
      acc1 += a1*Hf[s*128+64+lane];
    }
    out[wid*128+lane]=acc0;
    out[wid*128+64+lane]=acc1;
  } else {
    float iv = 1.f/sum[0];
    float acc = 0.f;
    int c = lane & 31;
    for (int i = rs + (lane>>5); i < re; i += 2){
      int s = esrc[i];
      float a = __expf(lrelu(asrc[s]+adl[0])-m[0])*iv;
      acc += a*Hf[s*32+c];
    }
    acc += __shfl_xor(acc, 32);
    if (lane<32) out[wid*32+lane]=acc;
  }
}

// ---------------- bias + ELU (+ residual) ----------------
template<bool RES>
__global__ void post_k(const float* __restrict__ in, const float* __restrict__ bias,
                       float* __restrict__ out, int total, int mask){
  int i = blockIdx.x*256 + threadIdx.x;
  if (i >= total) return;
  float v = in[i] + bias[i & mask];
  v = eluf(v);
  if (RES) v += out[i];
  out[i] = v;
}

// ---------------- final reg/cls heads ----------------
__global__ void heads_k(const float* __restrict__ h3, const float* __restrict__ rw, const float* __restrict__ rb,
                        const float* __restrict__ cw, const float* __restrict__ cb,
                        float* __restrict__ out, int n){
  int t = blockIdx.x*256 + threadIdx.x;
  int node = t >> 5, l = t & 31;
  if (node >= n) return;
  float v = h3[node*32 + l];
  float r = v*rw[l], c = v*cw[l];
  #pragma unroll
  for (int mask=16; mask; mask>>=1){ r += __shfl_xor(r,mask); c += __shfl_xor(c,mask); }
  if (l==0){ out[node]=r+rb[0]; out[n+node]=c+cb[0]; }
}

extern "C" void kernel_launch(void* const* d_in, const int* in_sizes, int n_in,
                              void* d_out, int out_size, void* d_ws, size_t ws_size,
                              hipStream_t stream){
  const float* x   = (const float*)d_in[0];
  const int*   ei  = (const int*)d_in[1];
  const float* W1  = (const float*)d_in[2];
  const float* aS1 = (const float*)d_in[3];
  const float* aD1 = (const float*)d_in[4];
  const float* b1  = (const float*)d_in[5];
  const float* W2  = (const float*)d_in[6];
  const float* aS2 = (const float*)d_in[7];
  const float* aD2 = (const float*)d_in[8];
  const float* b2  = (const float*)d_in[9];
  const float* W3  = (const float*)d_in[10];
  const float* aS3 = (const float*)d_in[11];
  const float* aD3 = (const float*)d_in[12];
  const float* b3  = (const float*)d_in[13];
  const float* rw  = (const float*)d_in[14];
  const float* rb  = (const float*)d_in[15];
  const float* cw  = (const float*)d_in[16];
  const float* cb  = (const float*)d_in[17];
  float* out = (float*)d_out;

  const int n    = in_sizes[0] / 16;   // 100000
  const int ne   = in_sizes[1] / 2;    // 1600000
  const int etot = ne + n;             // + self loops

  // workspace layout (~165 MB)
  float* A    = (float*)d_ws;                 // [n,128] layer input / residual
  float* B    = A  + (size_t)n*128;           // [n,128] transformed h
  float* Cc   = B  + (size_t)n*128;           // [n,128] aggregation output
  float* asrc = Cc + (size_t)n*128;           // [n,4]
  float* adst = asrc + (size_t)n*4;           // [n,4]
  int* deg    = (int*)(adst + (size_t)n*4);
  int* rowst  = deg + n;                      // [n+1]
  int* cursor = rowst + n + 1;                // [n]
  int* esrc   = cursor + n;                   // [etot]
  int* blksum = esrc + etot;                  // [64]

  // ---- CSR build ----
  hipMemsetAsync(deg, 0, (size_t)n*sizeof(int), stream);
  hist_k<<<CDIV(etot,256),256,0,stream>>>(ei, deg, ne, etot);
  int nblk = CDIV(n, SCHUNK);
  scan_part_k<<<nblk,256,0,stream>>>(deg, rowst, blksum, n);
  scan_top_k<<<1,256,0,stream>>>(blksum, nblk);
  scan_add_k<<<CDIV(n,256),256,0,stream>>>(rowst, blksum, cursor, n, etot);
  scatter_k<<<CDIV(etot,256),256,0,stream>>>(ei, cursor, esrc, ne, etot);

  // ---- layer 1 ----
  gemm_att_k<16,128,4,64><<<CDIV(n,64),256,0,stream>>>(x, W1, aS1, aD1, B, asrc, adst, n);
  agg_k<4><<<CDIV(n,4),256,0,stream>>>(B, asrc, adst, rowst, esrc, Cc, n);
  post_k<false><<<CDIV(n*128,256),256,0,stream>>>(Cc, b1, A, n*128, 127);

  // ---- layer 2 (+residual) ----
  gemm_att_k<128,128,4,64><<<CDIV(n,64),256,0,stream>>>(A, W2, aS2, aD2, B, asrc, adst, n);
  agg_k<4><<<CDIV(n,4),256,0,stream>>>(B, asrc, adst, rowst, esrc, Cc, n);
  post_k<true><<<CDIV(n*128,256),256,0,stream>>>(Cc, b2, A, n*128, 127);

  // ---- layer 3 (H=1, C=32) ----
  gemm_att_k<128,32,1,128><<<CDIV(n,128),256,0,stream>>>(A, W3, aS3, aD3, B, asrc, adst, n);
  agg_k<1><<<CDIV(n,4),256,0,stream>>>(B, asrc, adst, rowst, esrc, Cc, n);
  post_k<false><<<CDIV(n*32,256),256,0,stream>>>(Cc, b3, A, n*32, 31);

  // ---- heads ----
  heads_k<<<CDIV(n*32,256),256,0,stream>>>(A, rw, rb, cw, cb, out, n);
}

// Round 2
// 863.758 us; speedup vs baseline: 1.2730x; 1.2730x over previous
//
#include <hip/hip_runtime.h>
#include <hip/hip_bf16.h>
#include <cstdint>

#define CDIV(a,b) (((a)+(b)-1)/(b))

__device__ __forceinline__ float lrelu(float x){ return x > 0.f ? x : 0.2f*x; }
__device__ __forceinline__ float eluf(float x){ return x > 0.f ? x : __expf(x) - 1.f; }

// ---------------- CSR build (by dst) ----------------
__global__ void hist_k(const int* __restrict__ ei, int* __restrict__ deg, int ne, int etot){
  int e = blockIdx.x*256 + threadIdx.x;
  if (e >= etot) return;
  int d = (e < ne) ? ei[ne + e] : (e - ne);
  atomicAdd(&deg[d], 1);
}

constexpr int SCHUNK = 2048;

__global__ __launch_bounds__(256) void scan_part_k(const int* __restrict__ in, int* __restrict__ out,
                                                   int* __restrict__ blksum, int n){
  __shared__ int lds[256];
  int base = blockIdx.x*SCHUNK + threadIdx.x*8;
  int v[8]; int tsum = 0;
  #pragma unroll
  for (int k=0;k<8;k++){ int idx=base+k; int x=(idx<n)?in[idx]:0; v[k]=tsum; tsum+=x; }
  lds[threadIdx.x]=tsum; __syncthreads();
  for (int off=1; off<256; off<<=1){
    int y = (threadIdx.x>= (unsigned)off)? lds[threadIdx.x-off]:0;
    __syncthreads();
    lds[threadIdx.x]+=y;
    __syncthreads();
  }
  int excl = lds[threadIdx.x] - tsum;
  #pragma unroll
  for (int k=0;k<8;k++){ int idx=base+k; if(idx<n) out[idx]=excl+v[k]; }
  if (threadIdx.x==255) blksum[blockIdx.x]=lds[255];
}

__global__ __launch_bounds__(256) void scan_top_k(int* __restrict__ blksum, int nb){
  __shared__ int lds[256];
  int x = ((int)threadIdx.x<nb)? blksum[threadIdx.x]:0;
  lds[threadIdx.x]=x; __syncthreads();
  for (int off=1; off<256; off<<=1){
    int y=(threadIdx.x>=(unsigned)off)?lds[threadIdx.x-off]:0;
    __syncthreads();
    lds[threadIdx.x]+=y;
    __syncthreads();
  }
  if ((int)threadIdx.x<nb) blksum[threadIdx.x]=lds[threadIdx.x]-x;
}

__global__ void scan_add_k(int* __restrict__ rowstart, const int* __restrict__ blksum,
                           int* __restrict__ cursor, int n, int etot){
  int i = blockIdx.x*256+threadIdx.x;
  if (i<n){ int r = rowstart[i]+blksum[i/SCHUNK]; rowstart[i]=r; cursor[i]=r; }
  if (i==0) rowstart[n]=etot;
}

__global__ void scatter_k(const int* __restrict__ ei, int* __restrict__ cursor,
                          int* __restrict__ edge_src, int ne, int etot){
  int e = blockIdx.x*256+threadIdx.x;
  if (e>=etot) return;
  int s,d;
  if (e<ne){ s=ei[e]; d=ei[ne+e]; } else { s=e-ne; d=s; }
  int p = atomicAdd(&cursor[d],1);
  edge_src[p]=s;
}

// ---------------- GEMM + fused attention logits ----------------
template<int K, int M, int H, int NPB>
__global__ __launch_bounds__(256) void gemm_att_k(const float* __restrict__ X, const float* __restrict__ W,
    const float* __restrict__ attS, const float* __restrict__ attD,
    float* __restrict__ Hout, float* __restrict__ asrc, float* __restrict__ adst, int n){
  constexpr int CG = M/4;          // col-groups of 4 cols
  constexpr int P  = 256/CG;       // nodes in flight per iteration
  __shared__ float Wl[K*M];
  __shared__ float Xl[P*K];
  for (int i = threadIdx.x; i < K*M; i += 256) Wl[i] = W[i];
  const int cg  = threadIdx.x % CG;
  const int sub = threadIdx.x / CG;
  const int nodeBase = blockIdx.x * NPB;
  for (int t0 = 0; t0 < NPB; t0 += P){
    __syncthreads();
    for (int i = threadIdx.x; i < P*K; i += 256){
      int nn = nodeBase + t0 + i/K;
      Xl[i] = (nn < n) ? X[(nodeBase+t0)*K + i] : 0.f;
    }
    __syncthreads();
    float a0=0.f,a1=0.f,a2=0.f,a3=0.f;
    #pragma unroll 4
    for (int k=0;k<K;++k){
      float4 w = *(const float4*)&Wl[k*M + cg*4];
      float xv = Xl[sub*K + k];
      a0 += xv*w.x; a1 += xv*w.y; a2 += xv*w.z; a3 += xv*w.w;
    }
    int c0 = cg*4;
    float vs = a0*attS[c0]+a1*attS[c0+1]+a2*attS[c0+2]+a3*attS[c0+3];
    float vd = a0*attD[c0]+a1*attD[c0+1]+a2*attD[c0+2]+a3*attD[c0+3];
    #pragma unroll
    for (int mask=1; mask<8; mask<<=1){ vs+=__shfl_xor(vs,mask); vd+=__shfl_xor(vd,mask); }
    int node = nodeBase + t0 + sub;
    if (node < n){
      *(float4*)&Hout[node*M + c0] = make_float4(a0,a1,a2,a3);
      if ((cg & 7)==0){
        int head = cg>>3;
        asrc[node*H+head]=vs;
        adst[node*H+head]=vd;
      }
    }
  }
}

// ---------------- H=4 softmax + aggregation + bias + ELU (+residual), one wave per dst ----------------
template<bool RES>
__global__ __launch_bounds__(256) void agg4_k(const float* __restrict__ Hf, const float* __restrict__ asrc,
    const float* __restrict__ adst, const int* __restrict__ rowstart, const int* __restrict__ esrc,
    const float* __restrict__ bias, float* __restrict__ out, int n){
  int wid  = (int)((blockIdx.x*256 + threadIdx.x) >> 6);
  int lane = threadIdx.x & 63;
  if (wid >= n) return;
  wid = __builtin_amdgcn_readfirstlane(wid);          // wave-uniform -> SGPR addressing
  const int rs = rowstart[wid], re = rowstart[wid+1];

  float4 adv = *(const float4*)&adst[(size_t)wid*4];
  float adl[4] = {adv.x, adv.y, adv.z, adv.w};

  // phase 1: segment max
  float m[4] = {-1e30f,-1e30f,-1e30f,-1e30f};
  for (int i = rs + lane; i < re; i += 64){
    int s = esrc[i];
    float4 a4 = *(const float4*)&asrc[(size_t)s*4];
    m[0]=fmaxf(m[0], lrelu(a4.x+adl[0]));
    m[1]=fmaxf(m[1], lrelu(a4.y+adl[1]));
    m[2]=fmaxf(m[2], lrelu(a4.z+adl[2]));
    m[3]=fmaxf(m[3], lrelu(a4.w+adl[3]));
  }
  #pragma unroll
  for (int h=0; h<4; ++h){
    #pragma unroll
    for (int mask=32; mask; mask>>=1) m[h] = fmaxf(m[h], __shfl_xor(m[h], mask));
  }

  // phase 2: segment sum of exp
  float sum[4] = {0.f,0.f,0.f,0.f};
  for (int i = rs + lane; i < re; i += 64){
    int s = esrc[i];
    float4 a4 = *(const float4*)&asrc[(size_t)s*4];
    sum[0]+=__expf(lrelu(a4.x+adl[0])-m[0]);
    sum[1]+=__expf(lrelu(a4.y+adl[1])-m[1]);
    sum[2]+=__expf(lrelu(a4.z+adl[2])-m[2]);
    sum[3]+=__expf(lrelu(a4.w+adl[3])-m[3]);
  }
  #pragma unroll
  for (int h=0; h<4; ++h){
    #pragma unroll
    for (int mask=32; mask; mask>>=1) sum[h]+=__shfl_xor(sum[h],mask);
  }

  // phase 3: weighted gather, 4 edges in flight
  const bool hi = (lane & 32) != 0;
  const float ad0 = hi? adl[1]:adl[0], ad1 = hi? adl[3]:adl[2];
  const float mm0 = hi? m[1]:m[0],     mm1 = hi? m[3]:m[2];
  const float iv0 = 1.f/(hi? sum[1]:sum[0]), iv1 = 1.f/(hi? sum[3]:sum[2]);
  float acc0=0.f, acc1=0.f;
  int i = rs;
  for (; i+4 <= re; i += 4){
    int s0=esrc[i], s1=esrc[i+1], s2=esrc[i+2], s3=esrc[i+3];
    float4 av0 = *(const float4*)&asrc[(size_t)s0*4];
    float4 av1 = *(const float4*)&asrc[(size_t)s1*4];
    float4 av2 = *(const float4*)&asrc[(size_t)s2*4];
    float4 av3 = *(const float4*)&asrc[(size_t)s3*4];
    const float* p0 = &Hf[(size_t)s0*128 + lane];
    const float* p1 = &Hf[(size_t)s1*128 + lane];
    const float* p2 = &Hf[(size_t)s2*128 + lane];
    const float* p3 = &Hf[(size_t)s3*128 + lane];
    float h00=p0[0], h01=p0[64];
    float h10=p1[0], h11=p1[64];
    float h20=p2[0], h21=p2[64];
    float h30=p3[0], h31=p3[64];
    float e00=__expf(lrelu((hi?av0.y:av0.x)+ad0)-mm0)*iv0;
    float e01=__expf(lrelu((hi?av0.w:av0.z)+ad1)-mm1)*iv1;
    float e10=__expf(lrelu((hi?av1.y:av1.x)+ad0)-mm0)*iv0;
    float e11=__expf(lrelu((hi?av1.w:av1.z)+ad1)-mm1)*iv1;
    float e20=__expf(lrelu((hi?av2.y:av2.x)+ad0)-mm0)*iv0;
    float e21=__expf(lrelu((hi?av2.w:av2.z)+ad1)-mm1)*iv1;
    float e30=__expf(lrelu((hi?av3.y:av3.x)+ad0)-mm0)*iv0;
    float e31=__expf(lrelu((hi?av3.w:av3.z)+ad1)-mm1)*iv1;
    acc0 += e00*h00 + e10*h10 + e20*h20 + e30*h30;
    acc1 += e01*h01 + e11*h11 + e21*h21 + e31*h31;
  }
  for (; i < re; ++i){
    int s = esrc[i];
    float4 av = *(const float4*)&asrc[(size_t)s*4];
    const float* p = &Hf[(size_t)s*128 + lane];
    float e0=__expf(lrelu((hi?av.y:av.x)+ad0)-mm0)*iv0;
    float e1=__expf(lrelu((hi?av.w:av.z)+ad1)-mm1)*iv1;
    acc0 += e0*p[0];
    acc1 += e1*p[64];
  }

  // fused epilogue: bias + ELU (+ residual), write layer output in place
  float v0 = eluf(acc0 + bias[lane]);
  float v1 = eluf(acc1 + bias[lane+64]);
  if (RES){
    v0 += out[(size_t)wid*128 + lane];
    v1 += out[(size_t)wid*128 + 64 + lane];
  }
  out[(size_t)wid*128 + lane]      = v0;
  out[(size_t)wid*128 + 64 + lane] = v1;
}

// ---------------- H=1 softmax + aggregation + bias + ELU + reg/cls heads ----------------
__global__ __launch_bounds__(256) void agg1_heads_k(const float* __restrict__ Hf, const float* __restrict__ asrc,
    const float* __restrict__ adst, const int* __restrict__ rowstart, const int* __restrict__ esrc,
    const float* __restrict__ bias,
    const float* __restrict__ rw, const float* __restrict__ rb,
    const float* __restrict__ cw, const float* __restrict__ cb,
    float* __restrict__ out, int n){
  int wid  = (int)((blockIdx.x*256 + threadIdx.x) >> 6);
  int lane = threadIdx.x & 63;
  if (wid >= n) return;
  wid = __builtin_amdgcn_readfirstlane(wid);
  const int rs = rowstart[wid], re = rowstart[wid+1];
  const float adl = adst[wid];

  float m = -1e30f;
  for (int i = rs + lane; i < re; i += 64) m = fmaxf(m, lrelu(asrc[esrc[i]]+adl));
  #pragma unroll
  for (int mask=32; mask; mask>>=1) m = fmaxf(m, __shfl_xor(m, mask));

  float sum = 0.f;
  for (int i = rs + lane; i < re; i += 64) sum += __expf(lrelu(asrc[esrc[i]]+adl)-m);
  #pragma unroll
  for (int mask=32; mask; mask>>=1) sum += __shfl_xor(sum, mask);
  const float iv = 1.f/sum;

  const int c = lane & 31, half = lane >> 5;
  float acc = 0.f;
  int i = rs;
  for (; i+4 <= re; i += 4){
    int sA = esrc[i+half];
    int sB = esrc[i+2+half];
    float aA = asrc[sA], aB = asrc[sB];
    float hA = Hf[(size_t)sA*32 + c], hB = Hf[(size_t)sB*32 + c];
    acc += __expf(lrelu(aA+adl)-m)*iv*hA;
    acc += __expf(lrelu(aB+adl)-m)*iv*hB;
  }
  for (; i+2 <= re; i += 2){
    int sA = esrc[i+half];
    acc += __expf(lrelu(asrc[sA]+adl)-m)*iv*Hf[(size_t)sA*32 + c];
  }
  if (i < re && half == 0){
    int sA = esrc[i];
    acc += __expf(lrelu(asrc[sA]+adl)-m)*iv*Hf[(size_t)sA*32 + c];
  }
  acc += __shfl_xor(acc, 32);           // combine the two half-wave partial sums

  float v = eluf(acc + bias[c]);
  float r = v*rw[c], cl = v*cw[c];
  #pragma unroll
  for (int mask=16; mask; mask>>=1){ r += __shfl_xor(r, mask); cl += __shfl_xor(cl, mask); }
  if (lane == 0){
    out[wid]     = r  + rb[0];
    out[n + wid] = cl + cb[0];
  }
}

extern "C" void kernel_launch(void* const* d_in, const int* in_sizes, int n_in,
                              void* d_out, int out_size, void* d_ws, size_t ws_size,
                              hipStream_t stream){
  const float* x   = (const float*)d_in[0];
  const int*   ei  = (const int*)d_in[1];
  const float* W1  = (const float*)d_in[2];
  const float* aS1 = (const float*)d_in[3];
  const float* aD1 = (const float*)d_in[4];
  const float* b1  = (const float*)d_in[5];
  const float* W2  = (const float*)d_in[6];
  const float* aS2 = (const float*)d_in[7];
  const float* aD2 = (const float*)d_in[8];
  const float* b2  = (const float*)d_in[9];
  const float* W3  = (const float*)d_in[10];
  const float* aS3 = (const float*)d_in[11];
  const float* aD3 = (const float*)d_in[12];
  const float* b3  = (const float*)d_in[13];
  const float* rw  = (const float*)d_in[14];
  const float* rb  = (const float*)d_in[15];
  const float* cw  = (const float*)d_in[16];
  const float* cb  = (const float*)d_in[17];
  float* out = (float*)d_out;

  const int n    = in_sizes[0] / 16;   // 100000
  const int ne   = in_sizes[1] / 2;    // 1600000
  const int etot = ne + n;             // + self loops

  // workspace layout
  float* A    = (float*)d_ws;                 // [n,128] layer input / residual
  float* B    = A  + (size_t)n*128;           // [n,128] transformed h
  float* Cc   = B  + (size_t)n*128;           // (unused, kept for layout stability)
  float* asrc = Cc + (size_t)n*128;           // [n,4]
  float* adst = asrc + (size_t)n*4;           // [n,4]
  int* deg    = (int*)(adst + (size_t)n*4);
  int* rowst  = deg + n;                      // [n+1]
  int* cursor = rowst + n + 1;                // [n]
  int* esrc   = cursor + n;                   // [etot]
  int* blksum = esrc + etot;                  // [64]

  // ---- CSR build ----
  hipMemsetAsync(deg, 0, (size_t)n*sizeof(int), stream);
  hist_k<<<CDIV(etot,256),256,0,stream>>>(ei, deg, ne, etot);
  int nblk = CDIV(n, SCHUNK);
  scan_part_k<<<nblk,256,0,stream>>>(deg, rowst, blksum, n);
  scan_top_k<<<1,256,0,stream>>>(blksum, nblk);
  scan_add_k<<<CDIV(n,256),256,0,stream>>>(rowst, blksum, cursor, n, etot);
  scatter_k<<<CDIV(etot,256),256,0,stream>>>(ei, cursor, esrc, ne, etot);

  // ---- layer 1 ----
  gemm_att_k<16,128,4,64><<<CDIV(n,64),256,0,stream>>>(x, W1, aS1, aD1, B, asrc, adst, n);
  agg4_k<false><<<CDIV(n,4),256,0,stream>>>(B, asrc, adst, rowst, esrc, b1, A, n);

  // ---- layer 2 (+residual) ----
  gemm_att_k<128,128,4,64><<<CDIV(n,64),256,0,stream>>>(A, W2, aS2, aD2, B, asrc, adst, n);
  agg4_k<true><<<CDIV(n,4),256,0,stream>>>(B, asrc, adst, rowst, esrc, b2, A, n);

  // ---- layer 3 (H=1, C=32) + heads fused ----
  gemm_att_k<128,32,1,128><<<CDIV(n,128),256,0,stream>>>(A, W3, aS3, aD3, B, asrc, adst, n);
  agg1_heads_k<<<CDIV(n,4),256,0,stream>>>(B, asrc, adst, rowst, esrc, b3, rw, rb, cw, cb, out, n);
}

// Round 3
// 739.398 us; speedup vs baseline: 1.4872x; 1.1682x over previous
//
#include <hip/hip_runtime.h>
#include <hip/hip_bf16.h>
#include <cstdint>

#define CDIV(a,b) (((a)+(b)-1)/(b))

__device__ __forceinline__ float lrelu(float x){ return x > 0.f ? x : 0.2f*x; }
__device__ __forceinline__ float eluf(float x){ return x > 0.f ? x : __expf(x) - 1.f; }

// ---------------- CSR build (by dst) ----------------
__global__ void hist_k(const int* __restrict__ ei, int* __restrict__ deg, int ne, int etot){
  int e = blockIdx.x*256 + threadIdx.x;
  if (e >= etot) return;
  int d = (e < ne) ? ei[ne + e] : (e - ne);
  atomicAdd(&deg[d], 1);
}

constexpr int SCHUNK = 2048;

__global__ __launch_bounds__(256) void scan_part_k(const int* __restrict__ in, int* __restrict__ out,
                                                   int* __restrict__ blksum, int n){
  __shared__ int lds[256];
  int base = blockIdx.x*SCHUNK + threadIdx.x*8;
  int v[8]; int tsum = 0;
  #pragma unroll
  for (int k=0;k<8;k++){ int idx=base+k; int x=(idx<n)?in[idx]:0; v[k]=tsum; tsum+=x; }
  lds[threadIdx.x]=tsum; __syncthreads();
  for (int off=1; off<256; off<<=1){
    int y = (threadIdx.x>= (unsigned)off)? lds[threadIdx.x-off]:0;
    __syncthreads();
    lds[threadIdx.x]+=y;
    __syncthreads();
  }
  int excl = lds[threadIdx.x] - tsum;
  #pragma unroll
  for (int k=0;k<8;k++){ int idx=base+k; if(idx<n) out[idx]=excl+v[k]; }
  if (threadIdx.x==255) blksum[blockIdx.x]=lds[255];
}

__global__ __launch_bounds__(256) void scan_top_k(int* __restrict__ blksum, int nb){
  __shared__ int lds[256];
  int x = ((int)threadIdx.x<nb)? blksum[threadIdx.x]:0;
  lds[threadIdx.x]=x; __syncthreads();
  for (int off=1; off<256; off<<=1){
    int y=(threadIdx.x>=(unsigned)off)?lds[threadIdx.x-off]:0;
    __syncthreads();
    lds[threadIdx.x]+=y;
    __syncthreads();
  }
  if ((int)threadIdx.x<nb) blksum[threadIdx.x]=lds[threadIdx.x]-x;
}

__global__ void scan_add_k(int* __restrict__ rowstart, const int* __restrict__ blksum,
                           int* __restrict__ cursor, int n, int etot){
  int i = blockIdx.x*256+threadIdx.x;
  if (i<n){ int r = rowstart[i]+blksum[i/SCHUNK]; rowstart[i]=r; cursor[i]=r; }
  if (i==0) rowstart[n]=etot;
}

__global__ void scatter_k(const int* __restrict__ ei, int* __restrict__ cursor,
                          int* __restrict__ edge_src, int ne, int etot){
  int e = blockIdx.x*256+threadIdx.x;
  if (e>=etot) return;
  int s,d;
  if (e<ne){ s=ei[e]; d=ei[ne+e]; } else { s=e-ne; d=s; }
  int p = atomicAdd(&cursor[d],1);
  edge_src[p]=s;
}

// ---------------- register-tiled GEMM + fused attention logits ----------------
// h = X @ W  (X: [n,K], W: [K,M]).  Thread owns 8 cols x NPT nodes = 8*NPT accs.
// CG = M/8 col-groups, NG = 256/CG node-slots, node tile NT = NG*NPT.
template<int K, int KC, int M, int NPT, int H>
__global__ __launch_bounds__(256) void gemm_att_k(const float* __restrict__ X, const float* __restrict__ W,
    const float* __restrict__ attS, const float* __restrict__ attD,
    float* __restrict__ Hout, float* __restrict__ asrc, float* __restrict__ adst, int n){
  constexpr int CG = M/8;
  constexpr int NG = 256/CG;
  constexpr int NT = NG*NPT;
  constexpr int XS = KC + 4;            // padded X stride (words); keeps 16B align, breaks bank aliasing
  __shared__ float Xl[NT*XS];
  __shared__ float Wl[KC*M];

  const int tid = threadIdx.x;
  const int cg  = tid % CG;
  const int nd  = tid / CG;
  const int base = blockIdx.x * NT;

  float acc[NPT][8];
  #pragma unroll
  for (int j=0;j<NPT;++j)
    #pragma unroll
    for (int c=0;c<8;++c) acc[j][c]=0.f;

  for (int kc0 = 0; kc0 < K; kc0 += KC){
    __syncthreads();
    // stage X chunk [NT][KC] (float4 granularity)
    for (int i = tid; i < NT*KC/4; i += 256){
      int node = i / (KC/4);
      int k4   = i % (KC/4);
      float4 v = make_float4(0.f,0.f,0.f,0.f);
      if (base + node < n) v = *(const float4*)&X[(size_t)(base+node)*K + kc0 + k4*4];
      *(float4*)&Xl[node*XS + k4*4] = v;
    }
    // stage W chunk [KC][M] (contiguous rows)
    const float* Wsrc = W + (size_t)kc0*M;
    for (int i = tid; i < KC*M/4; i += 256)
      *(float4*)&Wl[i*4] = *(const float4*)&Wsrc[i*4];
    __syncthreads();

    #pragma unroll 4
    for (int k4 = 0; k4 < KC/4; ++k4){
      float4 xv[NPT];
      #pragma unroll
      for (int j=0;j<NPT;++j) xv[j] = *(const float4*)&Xl[(nd + NG*j)*XS + k4*4];
      #pragma unroll
      for (int kk=0;kk<4;++kk){
        float4 w0 = *(const float4*)&Wl[(k4*4+kk)*M + cg*8];
        float4 w1 = *(const float4*)&Wl[(k4*4+kk)*M + cg*8 + 4];
        #pragma unroll
        for (int j=0;j<NPT;++j){
          float x = ((const float*)&xv[j])[kk];
          acc[j][0] += x*w0.x; acc[j][1] += x*w0.y; acc[j][2] += x*w0.z; acc[j][3] += x*w0.w;
          acc[j][4] += x*w1.x; acc[j][5] += x*w1.y; acc[j][6] += x*w1.z; acc[j][7] += x*w1.w;
        }
      }
    }
  }

  // epilogue: store H, fused attention logits
  const int c0 = cg*8;
  float s0=attS[c0],s1=attS[c0+1],s2=attS[c0+2],s3=attS[c0+3],
        s4=attS[c0+4],s5=attS[c0+5],s6=attS[c0+6],s7=attS[c0+7];
  float d0=attD[c0],d1=attD[c0+1],d2=attD[c0+2],d3=attD[c0+3],
        d4=attD[c0+4],d5=attD[c0+5],d6=attD[c0+6],d7=attD[c0+7];
  #pragma unroll
  for (int j=0;j<NPT;++j){
    int node = base + nd + NG*j;
    float vs = acc[j][0]*s0+acc[j][1]*s1+acc[j][2]*s2+acc[j][3]*s3
             + acc[j][4]*s4+acc[j][5]*s5+acc[j][6]*s6+acc[j][7]*s7;
    float vd = acc[j][0]*d0+acc[j][1]*d1+acc[j][2]*d2+acc[j][3]*d3
             + acc[j][4]*d4+acc[j][5]*d5+acc[j][6]*d6+acc[j][7]*d7;
    vs += __shfl_xor(vs,1); vs += __shfl_xor(vs,2);
    vd += __shfl_xor(vd,1); vd += __shfl_xor(vd,2);
    if (node < n){
      *(float4*)&Hout[(size_t)node*M + c0]     = make_float4(acc[j][0],acc[j][1],acc[j][2],acc[j][3]);
      *(float4*)&Hout[(size_t)node*M + c0 + 4] = make_float4(acc[j][4],acc[j][5],acc[j][6],acc[j][7]);
      if ((cg & 3)==0){
        int head = cg>>2;
        asrc[(size_t)node*H+head]=vs;
        adst[(size_t)node*H+head]=vd;
      }
    }
  }
}

// ---------------- H=4 softmax + aggregation + bias + ELU (+residual), one wave per dst ----------------
template<bool RES>
__global__ __launch_bounds__(256) void agg4_k(const float* __restrict__ Hf, const float* __restrict__ asrc,
    const float* __restrict__ adst, const int* __restrict__ rowstart, const int* __restrict__ esrc,
    const float* __restrict__ bias, float* __restrict__ out, int n){
  int wid  = (int)((blockIdx.x*256 + threadIdx.x) >> 6);
  int lane = threadIdx.x & 63;
  if (wid >= n) return;
  wid = __builtin_amdgcn_readfirstlane(wid);          // wave-uniform -> SGPR addressing
  const int rs = rowstart[wid], re = rowstart[wid+1];

  float4 adv = *(const float4*)&adst[(size_t)wid*4];
  float adl[4] = {adv.x, adv.y, adv.z, adv.w};

  // phase 1: segment max
  float m[4] = {-1e30f,-1e30f,-1e30f,-1e30f};
  for (int i = rs + lane; i < re; i += 64){
    int s = esrc[i];
    float4 a4 = *(const float4*)&asrc[(size_t)s*4];
    m[0]=fmaxf(m[0], lrelu(a4.x+adl[0]));
    m[1]=fmaxf(m[1], lrelu(a4.y+adl[1]));
    m[2]=fmaxf(m[2], lrelu(a4.z+adl[2]));
    m[3]=fmaxf(m[3], lrelu(a4.w+adl[3]));
  }
  #pragma unroll
  for (int h=0; h<4; ++h){
    #pragma unroll
    for (int mask=32; mask; mask>>=1) m[h] = fmaxf(m[h], __shfl_xor(m[h], mask));
  }

  // phase 2: segment sum of exp
  float sum[4] = {0.f,0.f,0.f,0.f};
  for (int i = rs + lane; i < re; i += 64){
    int s = esrc[i];
    float4 a4 = *(const float4*)&asrc[(size_t)s*4];
    sum[0]+=__expf(lrelu(a4.x+adl[0])-m[0]);
    sum[1]+=__expf(lrelu(a4.y+adl[1])-m[1]);
    sum[2]+=__expf(lrelu(a4.z+adl[2])-m[2]);
    sum[3]+=__expf(lrelu(a4.w+adl[3])-m[3]);
  }
  #pragma unroll
  for (int h=0; h<4; ++h){
    #pragma unroll
    for (int mask=32; mask; mask>>=1) sum[h]+=__shfl_xor(sum[h],mask);
  }

  // phase 3: weighted gather, 4 edges in flight
  const bool hi = (lane & 32) != 0;
  const float ad0 = hi? adl[1]:adl[0], ad1 = hi? adl[3]:adl[2];
  const float mm0 = hi? m[1]:m[0],     mm1 = hi? m[3]:m[2];
  const float iv0 = 1.f/(hi? sum[1]:sum[0]), iv1 = 1.f/(hi? sum[3]:sum[2]);
  float acc0=0.f, acc1=0.f;
  int i = rs;
  for (; i+4 <= re; i += 4){
    int s0=esrc[i], s1=esrc[i+1], s2=esrc[i+2], s3=esrc[i+3];
    float4 av0 = *(const float4*)&asrc[(size_t)s0*4];
    float4 av1 = *(const float4*)&asrc[(size_t)s1*4];
    float4 av2 = *(const float4*)&asrc[(size_t)s2*4];
    float4 av3 = *(const float4*)&asrc[(size_t)s3*4];
    const float* p0 = &Hf[(size_t)s0*128 + lane];
    const float* p1 = &Hf[(size_t)s1*128 + lane];
    const float* p2 = &Hf[(size_t)s2*128 + lane];
    const float* p3 = &Hf[(size_t)s3*128 + lane];
    float h00=p0[0], h01=p0[64];
    float h10=p1[0], h11=p1[64];
    float h20=p2[0], h21=p2[64];
    float h30=p3[0], h31=p3[64];
    float e00=__expf(lrelu((hi?av0.y:av0.x)+ad0)-mm0)*iv0;
    float e01=__expf(lrelu((hi?av0.w:av0.z)+ad1)-mm1)*iv1;
    float e10=__expf(lrelu((hi?av1.y:av1.x)+ad0)-mm0)*iv0;
    float e11=__expf(lrelu((hi?av1.w:av1.z)+ad1)-mm1)*iv1;
    float e20=__expf(lrelu((hi?av2.y:av2.x)+ad0)-mm0)*iv0;
    float e21=__expf(lrelu((hi?av2.w:av2.z)+ad1)-mm1)*iv1;
    float e30=__expf(lrelu((hi?av3.y:av3.x)+ad0)-mm0)*iv0;
    float e31=__expf(lrelu((hi?av3.w:av3.z)+ad1)-mm1)*iv1;
    acc0 += e00*h00 + e10*h10 + e20*h20 + e30*h30;
    acc1 += e01*h01 + e11*h11 + e21*h21 + e31*h31;
  }
  for (; i < re; ++i){
    int s = esrc[i];
    float4 av = *(const float4*)&asrc[(size_t)s*4];
    const float* p = &Hf[(size_t)s*128 + lane];
    float e0=__expf(lrelu((hi?av.y:av.x)+ad0)-mm0)*iv0;
    float e1=__expf(lrelu((hi?av.w:av.z)+ad1)-mm1)*iv1;
    acc0 += e0*p[0];
    acc1 += e1*p[64];
  }

  float v0 = eluf(acc0 + bias[lane]);
  float v1 = eluf(acc1 + bias[lane+64]);
  if (RES){
    v0 += out[(size_t)wid*128 + lane];
    v1 += out[(size_t)wid*128 + 64 + lane];
  }
  out[(size_t)wid*128 + lane]      = v0;
  out[(size_t)wid*128 + 64 + lane] = v1;
}

// ---------------- H=1 softmax + aggregation + bias + ELU + reg/cls heads ----------------
__global__ __launch_bounds__(256) void agg1_heads_k(const float* __restrict__ Hf, const float* __restrict__ asrc,
    const float* __restrict__ adst, const int* __restrict__ rowstart, const int* __restrict__ esrc,
    const float* __restrict__ bias,
    const float* __restrict__ rw, const float* __restrict__ rb,
    const float* __restrict__ cw, const float* __restrict__ cb,
    float* __restrict__ out, int n){
  int wid  = (int)((blockIdx.x*256 + threadIdx.x) >> 6);
  int lane = threadIdx.x & 63;
  if (wid >= n) return;
  wid = __builtin_amdgcn_readfirstlane(wid);
  const int rs = rowstart[wid], re = rowstart[wid+1];
  const float adl = adst[wid];

  float m = -1e30f;
  for (int i = rs + lane; i < re; i += 64) m = fmaxf(m, lrelu(asrc[esrc[i]]+adl));
  #pragma unroll
  for (int mask=32; mask; mask>>=1) m = fmaxf(m, __shfl_xor(m, mask));

  float sum = 0.f;
  for (int i = rs + lane; i < re; i += 64) sum += __expf(lrelu(asrc[esrc[i]]+adl)-m);
  #pragma unroll
  for (int mask=32; mask; mask>>=1) sum += __shfl_xor(sum, mask);
  const float iv = 1.f/sum;

  const int c = lane & 31, half = lane >> 5;
  float acc = 0.f;
  int i = rs;
  for (; i+4 <= re; i += 4){
    int sA = esrc[i+half];
    int sB = esrc[i+2+half];
    float aA = asrc[sA], aB = asrc[sB];
    float hA = Hf[(size_t)sA*32 + c], hB = Hf[(size_t)sB*32 + c];
    acc += __expf(lrelu(aA+adl)-m)*iv*hA;
    acc += __expf(lrelu(aB+adl)-m)*iv*hB;
  }
  for (; i+2 <= re; i += 2){
    int sA = esrc[i+half];
    acc += __expf(lrelu(asrc[sA]+adl)-m)*iv*Hf[(size_t)sA*32 + c];
  }
  if (i < re && half == 0){
    int sA = esrc[i];
    acc += __expf(lrelu(asrc[sA]+adl)-m)*iv*Hf[(size_t)sA*32 + c];
  }
  acc += __shfl_xor(acc, 32);

  float v = eluf(acc + bias[c]);
  float r = v*rw[c], cl = v*cw[c];
  #pragma unroll
  for (int mask=16; mask; mask>>=1){ r += __shfl_xor(r, mask); cl += __shfl_xor(cl, mask); }
  if (lane == 0){
    out[wid]     = r  + rb[0];
    out[n + wid] = cl + cb[0];
  }
}

extern "C" void kernel_launch(void* const* d_in, const int* in_sizes, int n_in,
                              void* d_out, int out_size, void* d_ws, size_t ws_size,
                              hipStream_t stream){
  const float* x   = (const float*)d_in[0];
  const int*   ei  = (const int*)d_in[1];
  const float* W1  = (const float*)d_in[2];
  const float* aS1 = (const float*)d_in[3];
  const float* aD1 = (const float*)d_in[4];
  const float* b1  = (const float*)d_in[5];
  const float* W2  = (const float*)d_in[6];
  const float* aS2 = (const float*)d_in[7];
  const float* aD2 = (const float*)d_in[8];
  const float* b2  = (const float*)d_in[9];
  const float* W3  = (const float*)d_in[10];
  const float* aS3 = (const float*)d_in[11];
  const float* aD3 = (const float*)d_in[12];
  const float* b3  = (const float*)d_in[13];
  const float* rw  = (const float*)d_in[14];
  const float* rb  = (const float*)d_in[15];
  const float* cw  = (const float*)d_in[16];
  const float* cb  = (const float*)d_in[17];
  float* out = (float*)d_out;

  const int n    = in_sizes[0] / 16;   // 100000
  const int ne   = in_sizes[1] / 2;    // 1600000
  const int etot = ne + n;             // + self loops

  // workspace layout
  float* A    = (float*)d_ws;                 // [n,128] layer input / residual
  float* B    = A  + (size_t)n*128;           // [n,128] transformed h
  float* Cc   = B  + (size_t)n*128;           // (unused, layout stability)
  float* asrc = Cc + (size_t)n*128;           // [n,4]
  float* adst = asrc + (size_t)n*4;           // [n,4]
  int* deg    = (int*)(adst + (size_t)n*4);
  int* rowst  = deg + n;                      // [n+1]
  int* cursor = rowst + n + 1;                // [n]
  int* esrc   = cursor + n;                   // [etot]
  int* blksum = esrc + etot;                  // [64]

  // ---- CSR build ----
  hipMemsetAsync(deg, 0, (size_t)n*sizeof(int), stream);
  hist_k<<<CDIV(etot,256),256,0,stream>>>(ei, deg, ne, etot);
  int nblk = CDIV(n, SCHUNK);
  scan_part_k<<<nblk,256,0,stream>>>(deg, rowst, blksum, n);
  scan_top_k<<<1,256,0,stream>>>(blksum, nblk);
  scan_add_k<<<CDIV(n,256),256,0,stream>>>(rowst, blksum, cursor, n, etot);
  scatter_k<<<CDIV(etot,256),256,0,stream>>>(ei, cursor, esrc, ne, etot);

  // ---- layer 1 ----  (K=16, M=128, NPT=4 -> NT=64)
  gemm_att_k<16,16,128,4,4><<<CDIV(n,64),256,0,stream>>>(x, W1, aS1, aD1, B, asrc, adst, n);
  agg4_k<false><<<CDIV(n,4),256,0,stream>>>(B, asrc, adst, rowst, esrc, b1, A, n);

  // ---- layer 2 (+residual) ----  (K=128, KC=32, M=128, NPT=4 -> NT=64)
  gemm_att_k<128,32,128,4,4><<<CDIV(n,64),256,0,stream>>>(A, W2, aS2, aD2, B, asrc, adst, n);
  agg4_k<true><<<CDIV(n,4),256,0,stream>>>(B, asrc, adst, rowst, esrc, b2, A, n);

  // ---- layer 3 (K=128, M=32, NPT=1 -> NT=64) + heads fused ----
  gemm_att_k<128,32,32,1,1><<<CDIV(n,64),256,0,stream>>>(A, W3, aS3, aD3, B, asrc, adst, n);
  agg1_heads_k<<<CDIV(n,4),256,0,stream>>>(B, asrc, adst, rowst, esrc, b3, rw, rb, cw, cb, out, n);
}

// Round 4
// 675.136 us; speedup vs baseline: 1.6287x; 1.0952x over previous
//
#include <hip/hip_runtime.h>
#include <hip/hip_bf16.h>
#include <cstdint>

#define CDIV(a,b) (((a)+(b)-1)/(b))

__device__ __forceinline__ float lrelu(float x){ return x > 0.f ? x : 0.2f*x; }
__device__ __forceinline__ float eluf(float x){ return x > 0.f ? x : __expf(x) - 1.f; }
__device__ __forceinline__ unsigned short f2bf(float f){          // RNE float->bf16
  unsigned x = __float_as_uint(f);
  return (unsigned short)((x + 0x7fffu + ((x >> 16) & 1u)) >> 16);
}
__device__ __forceinline__ float bf2f(unsigned short u){ return __uint_as_float(((unsigned)u) << 16); }

// ---------------- CSR build (by dst) ----------------
__global__ void hist_k(const int* __restrict__ ei, int* __restrict__ deg, int ne, int etot){
  int e = blockIdx.x*256 + threadIdx.x;
  if (e >= etot) return;
  int d = (e < ne) ? ei[ne + e] : (e - ne);
  atomicAdd(&deg[d], 1);
}

constexpr int SCHUNK = 2048;

__global__ __launch_bounds__(256) void scan_part_k(const int* __restrict__ in, int* __restrict__ out,
                                                   int* __restrict__ blksum, int n){
  __shared__ int lds[256];
  int base = blockIdx.x*SCHUNK + threadIdx.x*8;
  int v[8]; int tsum = 0;
  #pragma unroll
  for (int k=0;k<8;k++){ int idx=base+k; int x=(idx<n)?in[idx]:0; v[k]=tsum; tsum+=x; }
  lds[threadIdx.x]=tsum; __syncthreads();
  for (int off=1; off<256; off<<=1){
    int y = (threadIdx.x>= (unsigned)off)? lds[threadIdx.x-off]:0;
    __syncthreads();
    lds[threadIdx.x]+=y;
    __syncthreads();
  }
  int excl = lds[threadIdx.x] - tsum;
  #pragma unroll
  for (int k=0;k<8;k++){ int idx=base+k; if(idx<n) out[idx]=excl+v[k]; }
  if (threadIdx.x==255) blksum[blockIdx.x]=lds[255];
}

__global__ __launch_bounds__(256) void scan_top_k(int* __restrict__ blksum, int nb){
  __shared__ int lds[256];
  int x = ((int)threadIdx.x<nb)? blksum[threadIdx.x]:0;
  lds[threadIdx.x]=x; __syncthreads();
  for (int off=1; off<256; off<<=1){
    int y=(threadIdx.x>=(unsigned)off)?lds[threadIdx.x-off]:0;
    __syncthreads();
    lds[threadIdx.x]+=y;
    __syncthreads();
  }
  if ((int)threadIdx.x<nb) blksum[threadIdx.x]=lds[threadIdx.x]-x;
}

__global__ void scan_add_k(int* __restrict__ rowstart, const int* __restrict__ blksum,
                           int* __restrict__ cursor, int n, int etot){
  int i = blockIdx.x*256+threadIdx.x;
  if (i<n){ int r = rowstart[i]+blksum[i/SCHUNK]; rowstart[i]=r; cursor[i]=r; }
  if (i==0) rowstart[n]=etot;
}

// range-split scatter: only edges with dst in [lo,hi) participate ->
// esrc window (~1.7MB) and cursor slice stay L2-resident, full-line writeback.
__global__ void scatter_k(const int* __restrict__ ei, int* __restrict__ cursor,
                          int* __restrict__ edge_src, int ne, int etot, int lo, int hi){
  int e = blockIdx.x*256+threadIdx.x;
  if (e>=etot) return;
  int s,d;
  if (e<ne){ s=ei[e]; d=ei[ne+e]; } else { s=e-ne; d=s; }
  if (d < lo || d >= hi) return;
  int p = atomicAdd(&cursor[d],1);
  edge_src[p]=s;
}

// ---------------- register-tiled GEMM + fused attention logits (bf16 H output) ----------------
template<int K, int KC, int M, int NPT, int H>
__global__ __launch_bounds__(256) void gemm_att_k(const float* __restrict__ X, const float* __restrict__ W,
    const float* __restrict__ attS, const float* __restrict__ attD,
    unsigned short* __restrict__ Hb, float* __restrict__ asrc, float* __restrict__ adst, int n){
  constexpr int CG = M/8;
  constexpr int NG = 256/CG;
  constexpr int NT = NG*NPT;
  constexpr int XS = KC + 4;
  __shared__ float Xl[NT*XS];
  __shared__ float Wl[KC*M];

  const int tid = threadIdx.x;
  const int cg  = tid % CG;
  const int nd  = tid / CG;
  const int base = blockIdx.x * NT;

  float acc[NPT][8];
  #pragma unroll
  for (int j=0;j<NPT;++j)
    #pragma unroll
    for (int c=0;c<8;++c) acc[j][c]=0.f;

  for (int kc0 = 0; kc0 < K; kc0 += KC){
    __syncthreads();
    for (int i = tid; i < NT*KC/4; i += 256){
      int node = i / (KC/4);
      int k4   = i % (KC/4);
      float4 v = make_float4(0.f,0.f,0.f,0.f);
      if (base + node < n) v = *(const float4*)&X[(size_t)(base+node)*K + kc0 + k4*4];
      *(float4*)&Xl[node*XS + k4*4] = v;
    }
    const float* Wsrc = W + (size_t)kc0*M;
    for (int i = tid; i < KC*M/4; i += 256)
      *(float4*)&Wl[i*4] = *(const float4*)&Wsrc[i*4];
    __syncthreads();

    #pragma unroll 4
    for (int k4 = 0; k4 < KC/4; ++k4){
      float4 xv[NPT];
      #pragma unroll
      for (int j=0;j<NPT;++j) xv[j] = *(const float4*)&Xl[(nd + NG*j)*XS + k4*4];
      #pragma unroll
      for (int kk=0;kk<4;++kk){
        float4 w0 = *(const float4*)&Wl[(k4*4+kk)*M + cg*8];
        float4 w1 = *(const float4*)&Wl[(k4*4+kk)*M + cg*8 + 4];
        #pragma unroll
        for (int j=0;j<NPT;++j){
          float x = ((const float*)&xv[j])[kk];
          acc[j][0] += x*w0.x; acc[j][1] += x*w0.y; acc[j][2] += x*w0.z; acc[j][3] += x*w0.w;
          acc[j][4] += x*w1.x; acc[j][5] += x*w1.y; acc[j][6] += x*w1.z; acc[j][7] += x*w1.w;
        }
      }
    }
  }

  const int c0 = cg*8;
  float s0=attS[c0],s1=attS[c0+1],s2=attS[c0+2],s3=attS[c0+3],
        s4=attS[c0+4],s5=attS[c0+5],s6=attS[c0+6],s7=attS[c0+7];
  float d0=attD[c0],d1=attD[c0+1],d2=attD[c0+2],d3=attD[c0+3],
        d4=attD[c0+4],d5=attD[c0+5],d6=attD[c0+6],d7=attD[c0+7];
  #pragma unroll
  for (int j=0;j<NPT;++j){
    int node = base + nd + NG*j;
    float vs = acc[j][0]*s0+acc[j][1]*s1+acc[j][2]*s2+acc[j][3]*s3
             + acc[j][4]*s4+acc[j][5]*s5+acc[j][6]*s6+acc[j][7]*s7;
    float vd = acc[j][0]*d0+acc[j][1]*d1+acc[j][2]*d2+acc[j][3]*d3
             + acc[j][4]*d4+acc[j][5]*d5+acc[j][6]*d6+acc[j][7]*d7;
    vs += __shfl_xor(vs,1); vs += __shfl_xor(vs,2);
    vd += __shfl_xor(vd,1); vd += __shfl_xor(vd,2);
    if (node < n){
      uint4 pk;
      pk.x = (unsigned)f2bf(acc[j][0]) | ((unsigned)f2bf(acc[j][1])<<16);
      pk.y = (unsigned)f2bf(acc[j][2]) | ((unsigned)f2bf(acc[j][3])<<16);
      pk.z = (unsigned)f2bf(acc[j][4]) | ((unsigned)f2bf(acc[j][5])<<16);
      pk.w = (unsigned)f2bf(acc[j][6]) | ((unsigned)f2bf(acc[j][7])<<16);
      *(uint4*)&Hb[(size_t)node*M + c0] = pk;
      if ((cg & 3)==0){
        int head = cg>>2;
        asrc[(size_t)node*H+head]=vs;
        adst[(size_t)node*H+head]=vd;
      }
    }
  }
}

// ---------------- H=4 softmax + aggregation + bias + ELU (+residual), one wave per dst ----------------
template<bool RES>
__global__ __launch_bounds__(256) void agg4_k(const unsigned short* __restrict__ Hb, const float* __restrict__ asrc,
    const float* __restrict__ adst, const int* __restrict__ rowstart, const int* __restrict__ esrc,
    const float* __restrict__ bias, float* __restrict__ out, int n){
  int wid  = (int)((blockIdx.x*256 + threadIdx.x) >> 6);
  int lane = threadIdx.x & 63;
  if (wid >= n) return;
  wid = __builtin_amdgcn_readfirstlane(wid);
  const int rs = rowstart[wid], re = rowstart[wid+1];

  float4 adv = *(const float4*)&adst[(size_t)wid*4];
  float adl[4] = {adv.x, adv.y, adv.z, adv.w};

  // phase 1: segment max
  float m[4] = {-1e30f,-1e30f,-1e30f,-1e30f};
  for (int i = rs + lane; i < re; i += 64){
    int s = esrc[i];
    float4 a4 = *(const float4*)&asrc[(size_t)s*4];
    m[0]=fmaxf(m[0], lrelu(a4.x+adl[0]));
    m[1]=fmaxf(m[1], lrelu(a4.y+adl[1]));
    m[2]=fmaxf(m[2], lrelu(a4.z+adl[2]));
    m[3]=fmaxf(m[3], lrelu(a4.w+adl[3]));
  }
  #pragma unroll
  for (int h=0; h<4; ++h){
    #pragma unroll
    for (int mask=32; mask; mask>>=1) m[h] = fmaxf(m[h], __shfl_xor(m[h], mask));
  }

  // phase 2: segment sum of exp
  float sum[4] = {0.f,0.f,0.f,0.f};
  for (int i = rs + lane; i < re; i += 64){
    int s = esrc[i];
    float4 a4 = *(const float4*)&asrc[(size_t)s*4];
    sum[0]+=__expf(lrelu(a4.x+adl[0])-m[0]);
    sum[1]+=__expf(lrelu(a4.y+adl[1])-m[1]);
    sum[2]+=__expf(lrelu(a4.z+adl[2])-m[2]);
    sum[3]+=__expf(lrelu(a4.w+adl[3])-m[3]);
  }
  #pragma unroll
  for (int h=0; h<4; ++h){
    #pragma unroll
    for (int mask=32; mask; mask>>=1) sum[h]+=__shfl_xor(sum[h],mask);
  }

  // phase 3: lane owns cols {2*lane, 2*lane+1}; head = lane>>4; 1 exp/lane/edge
  const int head = lane >> 4;
  const float ad = adl[head], mm = m[head], iv = 1.f/sum[head];
  float acc0=0.f, acc1=0.f;
  int i = rs;
  for (; i+4 <= re; i += 4){
    int s0=esrc[i], s1=esrc[i+1], s2=esrc[i+2], s3=esrc[i+3];
    float a0 = asrc[(size_t)s0*4+head];
    float a1 = asrc[(size_t)s1*4+head];
    float a2 = asrc[(size_t)s2*4+head];
    float a3 = asrc[(size_t)s3*4+head];
    ushort2 h0 = ((const ushort2*)(Hb + (size_t)s0*128))[lane];
    ushort2 h1 = ((const ushort2*)(Hb + (size_t)s1*128))[lane];
    ushort2 h2 = ((const ushort2*)(Hb + (size_t)s2*128))[lane];
    ushort2 h3 = ((const ushort2*)(Hb + (size_t)s3*128))[lane];
    float e0=__expf(lrelu(a0+ad)-mm)*iv;
    float e1=__expf(lrelu(a1+ad)-mm)*iv;
    float e2=__expf(lrelu(a2+ad)-mm)*iv;
    float e3=__expf(lrelu(a3+ad)-mm)*iv;
    acc0 += e0*bf2f(h0.x) + e1*bf2f(h1.x) + e2*bf2f(h2.x) + e3*bf2f(h3.x);
    acc1 += e0*bf2f(h0.y) + e1*bf2f(h1.y) + e2*bf2f(h2.y) + e3*bf2f(h3.y);
  }
  for (; i < re; ++i){
    int s = esrc[i];
    float a = asrc[(size_t)s*4+head];
    ushort2 hv = ((const ushort2*)(Hb + (size_t)s*128))[lane];
    float e = __expf(lrelu(a+ad)-mm)*iv;
    acc0 += e*bf2f(hv.x);
    acc1 += e*bf2f(hv.y);
  }

  float2 bv = *(const float2*)&bias[2*lane];
  float v0 = eluf(acc0 + bv.x);
  float v1 = eluf(acc1 + bv.y);
  if (RES){
    float2 rv = *(const float2*)&out[(size_t)wid*128 + 2*lane];
    v0 += rv.x; v1 += rv.y;
  }
  *(float2*)&out[(size_t)wid*128 + 2*lane] = make_float2(v0, v1);
}

// ---------------- H=1 softmax + aggregation + bias + ELU + reg/cls heads ----------------
__global__ __launch_bounds__(256) void agg1_heads_k(const unsigned short* __restrict__ Hb, const float* __restrict__ asrc,
    const float* __restrict__ adst, const int* __restrict__ rowstart, const int* __restrict__ esrc,
    const float* __restrict__ bias,
    const float* __restrict__ rw, const float* __restrict__ rb,
    const float* __restrict__ cw, const float* __restrict__ cb,
    float* __restrict__ out, int n){
  int wid  = (int)((blockIdx.x*256 + threadIdx.x) >> 6);
  int lane = threadIdx.x & 63;
  if (wid >= n) return;
  wid = __builtin_amdgcn_readfirstlane(wid);
  const int rs = rowstart[wid], re = rowstart[wid+1];
  const float adl = adst[wid];

  float m = -1e30f;
  for (int i = rs + lane; i < re; i += 64) m = fmaxf(m, lrelu(asrc[esrc[i]]+adl));
  #pragma unroll
  for (int mask=32; mask; mask>>=1) m = fmaxf(m, __shfl_xor(m, mask));

  float sum = 0.f;
  for (int i = rs + lane; i < re; i += 64) sum += __expf(lrelu(asrc[esrc[i]]+adl)-m);
  #pragma unroll
  for (int mask=32; mask; mask>>=1) sum += __shfl_xor(sum, mask);
  const float iv = 1.f/sum;

  // phase 3: 4 edges in flight (one per 16-lane quarter); lane owns cols {2*c2, 2*c2+1}
  const int q = lane >> 4, c2 = lane & 15;
  float acc0 = 0.f, acc1 = 0.f;
  for (int i = rs; i < re; i += 4){
    int ei = i + q;
    if (ei < re){
      int s = esrc[ei];
      float a = asrc[s];
      float e = __expf(lrelu(a+adl)-m)*iv;
      ushort2 hv = ((const ushort2*)(Hb + (size_t)s*32))[c2];
      acc0 += e*bf2f(hv.x);
      acc1 += e*bf2f(hv.y);
    }
  }
  acc0 += __shfl_xor(acc0,16); acc0 += __shfl_xor(acc0,32);
  acc1 += __shfl_xor(acc1,16); acc1 += __shfl_xor(acc1,32);

  float2 bv = *(const float2*)&bias[2*c2];
  float v0 = eluf(acc0 + bv.x);
  float v1 = eluf(acc1 + bv.y);
  float r  = v0*rw[2*c2] + v1*rw[2*c2+1];
  float cl = v0*cw[2*c2] + v1*cw[2*c2+1];
  #pragma unroll
  for (int mask=1; mask<16; mask<<=1){ r += __shfl_xor(r, mask); cl += __shfl_xor(cl, mask); }
  if (lane == 0){
    out[wid]     = r  + rb[0];
    out[n + wid] = cl + cb[0];
  }
}

extern "C" void kernel_launch(void* const* d_in, const int* in_sizes, int n_in,
                              void* d_out, int out_size, void* d_ws, size_t ws_size,
                              hipStream_t stream){
  const float* x   = (const float*)d_in[0];
  const int*   ei  = (const int*)d_in[1];
  const float* W1  = (const float*)d_in[2];
  const float* aS1 = (const float*)d_in[3];
  const float* aD1 = (const float*)d_in[4];
  const float* b1  = (const float*)d_in[5];
  const float* W2  = (const float*)d_in[6];
  const float* aS2 = (const float*)d_in[7];
  const float* aD2 = (const float*)d_in[8];
  const float* b2  = (const float*)d_in[9];
  const float* W3  = (const float*)d_in[10];
  const float* aS3 = (const float*)d_in[11];
  const float* aD3 = (const float*)d_in[12];
  const float* b3  = (const float*)d_in[13];
  const float* rw  = (const float*)d_in[14];
  const float* rb  = (const float*)d_in[15];
  const float* cw  = (const float*)d_in[16];
  const float* cb  = (const float*)d_in[17];
  float* out = (float*)d_out;

  const int n    = in_sizes[0] / 16;   // 100000
  const int ne   = in_sizes[1] / 2;    // 1600000
  const int etot = ne + n;             // + self loops

  // workspace layout
  float* A    = (float*)d_ws;                 // [n,128] layer input / residual (fp32)
  float* Bf   = A  + (size_t)n*128;           // [n,128] bf16 h (uses half, keep slot)
  unsigned short* Hb = (unsigned short*)Bf;
  float* asrc = Bf + (size_t)n*128;           // [n,4]
  float* adst = asrc + (size_t)n*4;           // [n,4]
  int* deg    = (int*)(adst + (size_t)n*4);
  int* rowst  = deg + n;                      // [n+1]
  int* cursor = rowst + n + 1;                // [n]
  int* esrc   = cursor + n;                   // [etot]
  int* blksum = esrc + etot;                  // [64]

  // ---- CSR build ----
  hipMemsetAsync(deg, 0, (size_t)n*sizeof(int), stream);
  hist_k<<<CDIV(etot,256),256,0,stream>>>(ei, deg, ne, etot);
  int nblk = CDIV(n, SCHUNK);
  scan_part_k<<<nblk,256,0,stream>>>(deg, rowst, blksum, n);
  scan_top_k<<<1,256,0,stream>>>(blksum, nblk);
  scan_add_k<<<CDIV(n,256),256,0,stream>>>(rowst, blksum, cursor, n, etot);
  // range-split scatter: 4 passes over dst quartiles keep write windows L2-resident
  for (int p = 0; p < 4; ++p){
    int lo = (int)((size_t)n * p / 4);
    int hi = (int)((size_t)n * (p+1) / 4);
    scatter_k<<<CDIV(etot,256),256,0,stream>>>(ei, cursor, esrc, ne, etot, lo, hi);
  }

  // ---- layer 1 ----  (K=16, M=128, NPT=4 -> NT=64)
  gemm_att_k<16,16,128,4,4><<<CDIV(n,64),256,0,stream>>>(x, W1, aS1, aD1, Hb, asrc, adst, n);
  agg4_k<false><<<CDIV(n,4),256,0,stream>>>(Hb, asrc, adst, rowst, esrc, b1, A, n);

  // ---- layer 2 (+residual) ----  (K=128, KC=32, M=128, NPT=4 -> NT=64)
  gemm_att_k<128,32,128,4,4><<<CDIV(n,64),256,0,stream>>>(A, W2, aS2, aD2, Hb, asrc, adst, n);
  agg4_k<true><<<CDIV(n,4),256,0,stream>>>(Hb, asrc, adst, rowst, esrc, b2, A, n);

  // ---- layer 3 (K=128, M=32, NPT=1 -> NT=64) + heads fused ----
  gemm_att_k<128,32,32,1,1><<<CDIV(n,64),256,0,stream>>>(A, W3, aS3, aD3, Hb, asrc, adst, n);
  agg1_heads_k<<<CDIV(n,4),256,0,stream>>>(Hb, asrc, adst, rowst, esrc, b3, rw, rb, cw, cb, out, n);
}

// Round 5
// 576.537 us; speedup vs baseline: 1.9073x; 1.1710x over previous
//
#include <hip/hip_runtime.h>
#include <hip/hip_bf16.h>
#include <cstdint>

#define CDIV(a,b) (((a)+(b)-1)/(b))

__device__ __forceinline__ float lrelu(float x){ return x > 0.f ? x : 0.2f*x; }
__device__ __forceinline__ float eluf(float x){ return x > 0.f ? x : __expf(x) - 1.f; }
__device__ __forceinline__ unsigned short f2bf(float f){          // RNE float->bf16
  unsigned x = __float_as_uint(f);
  return (unsigned short)((x + 0x7fffu + ((x >> 16) & 1u)) >> 16);
}
__device__ __forceinline__ float bf2f(unsigned short u){ return __uint_as_float(((unsigned)u) << 16); }

// ---------------- CSR build (by dst) ----------------
__global__ void hist_k(const int* __restrict__ ei, int* __restrict__ deg, int ne, int etot){
  int e = blockIdx.x*256 + threadIdx.x;
  if (e >= etot) return;
  int d = (e < ne) ? ei[ne + e] : (e - ne);
  atomicAdd(&deg[d], 1);
}

constexpr int SCHUNK = 2048;

__global__ __launch_bounds__(256) void scan_part_k(const int* __restrict__ in, int* __restrict__ out,
                                                   int* __restrict__ blksum, int n){
  __shared__ int lds[256];
  int base = blockIdx.x*SCHUNK + threadIdx.x*8;
  int v[8]; int tsum = 0;
  #pragma unroll
  for (int k=0;k<8;k++){ int idx=base+k; int x=(idx<n)?in[idx]:0; v[k]=tsum; tsum+=x; }
  lds[threadIdx.x]=tsum; __syncthreads();
  for (int off=1; off<256; off<<=1){
    int y = (threadIdx.x>= (unsigned)off)? lds[threadIdx.x-off]:0;
    __syncthreads();
    lds[threadIdx.x]+=y;
    __syncthreads();
  }
  int excl = lds[threadIdx.x] - tsum;
  #pragma unroll
  for (int k=0;k<8;k++){ int idx=base+k; if(idx<n) out[idx]=excl+v[k]; }
  if (threadIdx.x==255) blksum[blockIdx.x]=lds[255];
}

__global__ __launch_bounds__(256) void scan_top_k(int* __restrict__ blksum, int nb){
  __shared__ int lds[256];
  int x = ((int)threadIdx.x<nb)? blksum[threadIdx.x]:0;
  lds[threadIdx.x]=x; __syncthreads();
  for (int off=1; off<256; off<<=1){
    int y=(threadIdx.x>=(unsigned)off)?lds[threadIdx.x-off]:0;
    __syncthreads();
    lds[threadIdx.x]+=y;
    __syncthreads();
  }
  if ((int)threadIdx.x<nb) blksum[threadIdx.x]=lds[threadIdx.x]-x;
}

__global__ void scan_add_k(int* __restrict__ rowstart, const int* __restrict__ blksum,
                           int* __restrict__ cursor, int n, int etot){
  int i = blockIdx.x*256+threadIdx.x;
  if (i<n){ int r = rowstart[i]+blksum[i/SCHUNK]; rowstart[i]=r; cursor[i]=r; }
  if (i==0) rowstart[n]=etot;
}

// range-split scatter: only edges with dst in [lo,hi) participate
__global__ void scatter_k(const int* __restrict__ ei, int* __restrict__ cursor,
                          int* __restrict__ edge_src, int ne, int etot, int lo, int hi){
  int e = blockIdx.x*256+threadIdx.x;
  if (e>=etot) return;
  int s,d;
  if (e<ne){ s=ei[e]; d=ei[ne+e]; } else { s=e-ne; d=s; }
  if (d < lo || d >= hi) return;
  int p = atomicAdd(&cursor[d],1);
  edge_src[p]=s;
}

// ---------------- register-tiled GEMM + fused attention logits (bf16 H output) ----------------
template<int K, int KC, int M, int NPT, int H>
__global__ __launch_bounds__(256) void gemm_att_k(const float* __restrict__ X, const float* __restrict__ W,
    const float* __restrict__ attS, const float* __restrict__ attD,
    unsigned short* __restrict__ Hb, float* __restrict__ asrc, float* __restrict__ adst, int n){
  constexpr int CG = M/8;
  constexpr int NG = 256/CG;
  constexpr int NT = NG*NPT;
  constexpr int XS = KC + 4;
  __shared__ float Xl[NT*XS];
  __shared__ float Wl[KC*M];

  const int tid = threadIdx.x;
  const int cg  = tid % CG;
  const int nd  = tid / CG;
  const int base = blockIdx.x * NT;

  float acc[NPT][8];
  #pragma unroll
  for (int j=0;j<NPT;++j)
    #pragma unroll
    for (int c=0;c<8;++c) acc[j][c]=0.f;

  for (int kc0 = 0; kc0 < K; kc0 += KC){
    __syncthreads();
    for (int i = tid; i < NT*KC/4; i += 256){
      int node = i / (KC/4);
      int k4   = i % (KC/4);
      float4 v = make_float4(0.f,0.f,0.f,0.f);
      if (base + node < n) v = *(const float4*)&X[(size_t)(base+node)*K + kc0 + k4*4];
      *(float4*)&Xl[node*XS + k4*4] = v;
    }
    const float* Wsrc = W + (size_t)kc0*M;
    for (int i = tid; i < KC*M/4; i += 256)
      *(float4*)&Wl[i*4] = *(const float4*)&Wsrc[i*4];
    __syncthreads();

    #pragma unroll 4
    for (int k4 = 0; k4 < KC/4; ++k4){
      float4 xv[NPT];
      #pragma unroll
      for (int j=0;j<NPT;++j) xv[j] = *(const float4*)&Xl[(nd + NG*j)*XS + k4*4];
      #pragma unroll
      for (int kk=0;kk<4;++kk){
        float4 w0 = *(const float4*)&Wl[(k4*4+kk)*M + cg*8];
        float4 w1 = *(const float4*)&Wl[(k4*4+kk)*M + cg*8 + 4];
        #pragma unroll
        for (int j=0;j<NPT;++j){
          float x = ((const float*)&xv[j])[kk];
          acc[j][0] += x*w0.x; acc[j][1] += x*w0.y; acc[j][2] += x*w0.z; acc[j][3] += x*w0.w;
          acc[j][4] += x*w1.x; acc[j][5] += x*w1.y; acc[j][6] += x*w1.z; acc[j][7] += x*w1.w;
        }
      }
    }
  }

  const int c0 = cg*8;
  float s0=attS[c0],s1=attS[c0+1],s2=attS[c0+2],s3=attS[c0+3],
        s4=attS[c0+4],s5=attS[c0+5],s6=attS[c0+6],s7=attS[c0+7];
  float d0=attD[c0],d1=attD[c0+1],d2=attD[c0+2],d3=attD[c0+3],
        d4=attD[c0+4],d5=attD[c0+5],d6=attD[c0+6],d7=attD[c0+7];
  #pragma unroll
  for (int j=0;j<NPT;++j){
    int node = base + nd + NG*j;
    float vs = acc[j][0]*s0+acc[j][1]*s1+acc[j][2]*s2+acc[j][3]*s3
             + acc[j][4]*s4+acc[j][5]*s5+acc[j][6]*s6+acc[j][7]*s7;
    float vd = acc[j][0]*d0+acc[j][1]*d1+acc[j][2]*d2+acc[j][3]*d3
             + acc[j][4]*d4+acc[j][5]*d5+acc[j][6]*d6+acc[j][7]*d7;
    vs += __shfl_xor(vs,1); vs += __shfl_xor(vs,2);
    vd += __shfl_xor(vd,1); vd += __shfl_xor(vd,2);
    if (node < n){
      uint4 pk;
      pk.x = (unsigned)f2bf(acc[j][0]) | ((unsigned)f2bf(acc[j][1])<<16);
      pk.y = (unsigned)f2bf(acc[j][2]) | ((unsigned)f2bf(acc[j][3])<<16);
      pk.z = (unsigned)f2bf(acc[j][4]) | ((unsigned)f2bf(acc[j][5])<<16);
      pk.w = (unsigned)f2bf(acc[j][6]) | ((unsigned)f2bf(acc[j][7])<<16);
      *(uint4*)&Hb[(size_t)node*M + c0] = pk;
      if ((cg & 3)==0){
        int head = cg>>2;
        asrc[(size_t)node*H+head]=vs;
        adst[(size_t)node*H+head]=vd;
      }
    }
  }
}

// ---------------- H=4 softmax + aggregation + bias + ELU (+residual), one wave per dst ----------------
// Fast path (deg<=64): single-pass logits, per-edge alpha normalized once and
// staged in LDS; phase-3 gather uses SGPR row base (readlane) + broadcast ds_read.
template<bool RES>
__global__ __launch_bounds__(256) void agg4_k(const unsigned short* __restrict__ Hb, const float* __restrict__ asrc,
    const float* __restrict__ adst, const int* __restrict__ rowstart, const int* __restrict__ esrc,
    const float* __restrict__ bias, float* __restrict__ out, int n){
  __shared__ float alphaS[4][64][4];
  const int w    = threadIdx.x >> 6;
  const int lane = threadIdx.x & 63;
  int wid  = (int)((blockIdx.x*256 + threadIdx.x) >> 6);
  if (wid >= n) return;
  wid = __builtin_amdgcn_readfirstlane(wid);
  const int rs = rowstart[wid], re = rowstart[wid+1];
  const int deg = re - rs;
  const float4 adv = *(const float4*)&adst[(size_t)wid*4];
  const int head = lane >> 4;

  float acc0 = 0.f, acc1 = 0.f;

  if (deg <= 64){
    // one edge per lane: load src + asrc ONCE, keep in registers
    int s = 0;
    float l0=-1e30f,l1=-1e30f,l2=-1e30f,l3=-1e30f;
    if (lane < deg){
      s = esrc[rs + lane];
      float4 a4 = *(const float4*)&asrc[(size_t)s*4];
      l0 = lrelu(a4.x+adv.x); l1 = lrelu(a4.y+adv.y);
      l2 = lrelu(a4.z+adv.z); l3 = lrelu(a4.w+adv.w);
    }
    float m0=l0,m1=l1,m2=l2,m3=l3;
    #pragma unroll
    for (int mask=32; mask; mask>>=1){
      m0=fmaxf(m0,__shfl_xor(m0,mask)); m1=fmaxf(m1,__shfl_xor(m1,mask));
      m2=fmaxf(m2,__shfl_xor(m2,mask)); m3=fmaxf(m3,__shfl_xor(m3,mask));
    }
    float e0=__expf(l0-m0), e1=__expf(l1-m1), e2=__expf(l2-m2), e3=__expf(l3-m3);
    float s0=e0,s1=e1,s2=e2,s3=e3;
    #pragma unroll
    for (int mask=32; mask; mask>>=1){
      s0+=__shfl_xor(s0,mask); s1+=__shfl_xor(s1,mask);
      s2+=__shfl_xor(s2,mask); s3+=__shfl_xor(s3,mask);
    }
    // normalized alpha to LDS (invalid lanes write 0)
    *(float4*)&alphaS[w][lane][0] = make_float4(e0/s0, e1/s1, e2/s2, e3/s3);

    int jj = 0;
    for (; jj+4 <= deg; jj += 4){
      int sj0 = __builtin_amdgcn_readlane(s, jj+0);
      int sj1 = __builtin_amdgcn_readlane(s, jj+1);
      int sj2 = __builtin_amdgcn_readlane(s, jj+2);
      int sj3 = __builtin_amdgcn_readlane(s, jj+3);
      ushort2 h0 = ((const ushort2*)(Hb + (size_t)sj0*128))[lane];
      ushort2 h1 = ((const ushort2*)(Hb + (size_t)sj1*128))[lane];
      ushort2 h2 = ((const ushort2*)(Hb + (size_t)sj2*128))[lane];
      ushort2 h3 = ((const ushort2*)(Hb + (size_t)sj3*128))[lane];
      float a0 = alphaS[w][jj+0][head];
      float a1 = alphaS[w][jj+1][head];
      float a2 = alphaS[w][jj+2][head];
      float a3 = alphaS[w][jj+3][head];
      acc0 += a0*bf2f(h0.x) + a1*bf2f(h1.x) + a2*bf2f(h2.x) + a3*bf2f(h3.x);
      acc1 += a0*bf2f(h0.y) + a1*bf2f(h1.y) + a2*bf2f(h2.y) + a3*bf2f(h3.y);
    }
    for (; jj < deg; ++jj){
      int sj = __builtin_amdgcn_readlane(s, jj);
      ushort2 hv = ((const ushort2*)(Hb + (size_t)sj*128))[lane];
      float a = alphaS[w][jj][head];
      acc0 += a*bf2f(hv.x);
      acc1 += a*bf2f(hv.y);
    }
  } else {
    // ---- slow path (deg>64): round-4 three-phase code ----
    float adl[4] = {adv.x, adv.y, adv.z, adv.w};
    float m[4] = {-1e30f,-1e30f,-1e30f,-1e30f};
    for (int i = rs + lane; i < re; i += 64){
      int s = esrc[i];
      float4 a4 = *(const float4*)&asrc[(size_t)s*4];
      m[0]=fmaxf(m[0], lrelu(a4.x+adl[0]));
      m[1]=fmaxf(m[1], lrelu(a4.y+adl[1]));
      m[2]=fmaxf(m[2], lrelu(a4.z+adl[2]));
      m[3]=fmaxf(m[3], lrelu(a4.w+adl[3]));
    }
    #pragma unroll
    for (int h=0; h<4; ++h){
      #pragma unroll
      for (int mask=32; mask; mask>>=1) m[h] = fmaxf(m[h], __shfl_xor(m[h], mask));
    }
    float sum[4] = {0.f,0.f,0.f,0.f};
    for (int i = rs + lane; i < re; i += 64){
      int s = esrc[i];
      float4 a4 = *(const float4*)&asrc[(size_t)s*4];
      sum[0]+=__expf(lrelu(a4.x+adl[0])-m[0]);
      sum[1]+=__expf(lrelu(a4.y+adl[1])-m[1]);
      sum[2]+=__expf(lrelu(a4.z+adl[2])-m[2]);
      sum[3]+=__expf(lrelu(a4.w+adl[3])-m[3]);
    }
    #pragma unroll
    for (int h=0; h<4; ++h){
      #pragma unroll
      for (int mask=32; mask; mask>>=1) sum[h]+=__shfl_xor(sum[h],mask);
    }
    const float ad = adl[head], mm = m[head], iv = 1.f/sum[head];
    int i = rs;
    for (; i+4 <= re; i += 4){
      int s0=esrc[i], s1=esrc[i+1], s2=esrc[i+2], s3=esrc[i+3];
      float a0 = asrc[(size_t)s0*4+head];
      float a1 = asrc[(size_t)s1*4+head];
      float a2 = asrc[(size_t)s2*4+head];
      float a3 = asrc[(size_t)s3*4+head];
      ushort2 h0 = ((const ushort2*)(Hb + (size_t)s0*128))[lane];
      ushort2 h1 = ((const ushort2*)(Hb + (size_t)s1*128))[lane];
      ushort2 h2 = ((const ushort2*)(Hb + (size_t)s2*128))[lane];
      ushort2 h3 = ((const ushort2*)(Hb + (size_t)s3*128))[lane];
      float e0=__expf(lrelu(a0+ad)-mm)*iv;
      float e1=__expf(lrelu(a1+ad)-mm)*iv;
      float e2=__expf(lrelu(a2+ad)-mm)*iv;
      float e3=__expf(lrelu(a3+ad)-mm)*iv;
      acc0 += e0*bf2f(h0.x) + e1*bf2f(h1.x) + e2*bf2f(h2.x) + e3*bf2f(h3.x);
      acc1 += e0*bf2f(h0.y) + e1*bf2f(h1.y) + e2*bf2f(h2.y) + e3*bf2f(h3.y);
    }
    for (; i < re; ++i){
      int s = esrc[i];
      float a = asrc[(size_t)s*4+head];
      ushort2 hv = ((const ushort2*)(Hb + (size_t)s*128))[lane];
      float e = __expf(lrelu(a+ad)-mm)*iv;
      acc0 += e*bf2f(hv.x);
      acc1 += e*bf2f(hv.y);
    }
  }

  float2 bv = *(const float2*)&bias[2*lane];
  float v0 = eluf(acc0 + bv.x);
  float v1 = eluf(acc1 + bv.y);
  if (RES){
    float2 rv = *(const float2*)&out[(size_t)wid*128 + 2*lane];
    v0 += rv.x; v1 += rv.y;
  }
  *(float2*)&out[(size_t)wid*128 + 2*lane] = make_float2(v0, v1);
}

// ---------------- H=1 softmax + aggregation + bias + ELU + reg/cls heads ----------------
__global__ __launch_bounds__(256) void agg1_heads_k(const unsigned short* __restrict__ Hb, const float* __restrict__ asrc,
    const float* __restrict__ adst, const int* __restrict__ rowstart, const int* __restrict__ esrc,
    const float* __restrict__ bias,
    const float* __restrict__ rw, const float* __restrict__ rb,
    const float* __restrict__ cw, const float* __restrict__ cb,
    float* __restrict__ out, int n){
  __shared__ float alphaS[4][64];
  const int w    = threadIdx.x >> 6;
  const int lane = threadIdx.x & 63;
  int wid  = (int)((blockIdx.x*256 + threadIdx.x) >> 6);
  if (wid >= n) return;
  wid = __builtin_amdgcn_readfirstlane(wid);
  const int rs = rowstart[wid], re = rowstart[wid+1];
  const int deg = re - rs;
  const float adl = adst[wid];
  const int q = lane >> 4, c2 = lane & 15;

  float acc0 = 0.f, acc1 = 0.f;

  if (deg <= 64){
    int s = 0;
    float l = -1e30f;
    if (lane < deg){
      s = esrc[rs + lane];
      l = lrelu(asrc[s]+adl);
    }
    float m = l;
    #pragma unroll
    for (int mask=32; mask; mask>>=1) m = fmaxf(m, __shfl_xor(m, mask));
    float e = __expf(l-m);
    float sum = e;
    #pragma unroll
    for (int mask=32; mask; mask>>=1) sum += __shfl_xor(sum, mask);
    alphaS[w][lane] = e/sum;          // invalid lanes -> 0

    for (int jj = 0; jj < deg; jj += 4){
      int idx = jj + q;               // per-quarter edge
      int sj = __shfl(s, idx);
      float av = alphaS[w][idx];      // 0 beyond deg
      ushort2 hv = ((const ushort2*)(Hb + (size_t)sj*32))[c2];
      acc0 += av*bf2f(hv.x);
      acc1 += av*bf2f(hv.y);
    }
  } else {
    float m = -1e30f;
    for (int i = rs + lane; i < re; i += 64) m = fmaxf(m, lrelu(asrc[esrc[i]]+adl));
    #pragma unroll
    for (int mask=32; mask; mask>>=1) m = fmaxf(m, __shfl_xor(m, mask));
    float sum = 0.f;
    for (int i = rs + lane; i < re; i += 64) sum += __expf(lrelu(asrc[esrc[i]]+adl)-m);
    #pragma unroll
    for (int mask=32; mask; mask>>=1) sum += __shfl_xor(sum, mask);
    const float iv = 1.f/sum;
    for (int i = rs; i < re; i += 4){
      int ei = i + q;
      if (ei < re){
        int s = esrc[ei];
        float a = asrc[s];
        float e = __expf(lrelu(a+adl)-m)*iv;
        ushort2 hv = ((const ushort2*)(Hb + (size_t)s*32))[c2];
        acc0 += e*bf2f(hv.x);
        acc1 += e*bf2f(hv.y);
      }
    }
  }

  acc0 += __shfl_xor(acc0,16); acc0 += __shfl_xor(acc0,32);
  acc1 += __shfl_xor(acc1,16); acc1 += __shfl_xor(acc1,32);

  float2 bv = *(const float2*)&bias[2*c2];
  float v0 = eluf(acc0 + bv.x);
  float v1 = eluf(acc1 + bv.y);
  float r  = v0*rw[2*c2] + v1*rw[2*c2+1];
  float cl = v0*cw[2*c2] + v1*cw[2*c2+1];
  #pragma unroll
  for (int mask=1; mask<16; mask<<=1){ r += __shfl_xor(r, mask); cl += __shfl_xor(cl, mask); }
  if (lane == 0){
    out[wid]     = r  + rb[0];
    out[n + wid] = cl + cb[0];
  }
}

extern "C" void kernel_launch(void* const* d_in, const int* in_sizes, int n_in,
                              void* d_out, int out_size, void* d_ws, size_t ws_size,
                              hipStream_t stream){
  const float* x   = (const float*)d_in[0];
  const int*   ei  = (const int*)d_in[1];
  const float* W1  = (const float*)d_in[2];
  const float* aS1 = (const float*)d_in[3];
  const float* aD1 = (const float*)d_in[4];
  const float* b1  = (const float*)d_in[5];
  const float* W2  = (const float*)d_in[6];
  const float* aS2 = (const float*)d_in[7];
  const float* aD2 = (const float*)d_in[8];
  const float* b2  = (const float*)d_in[9];
  const float* W3  = (const float*)d_in[10];
  const float* aS3 = (const float*)d_in[11];
  const float* aD3 = (const float*)d_in[12];
  const float* b3  = (const float*)d_in[13];
  const float* rw  = (const float*)d_in[14];
  const float* rb  = (const float*)d_in[15];
  const float* cw  = (const float*)d_in[16];
  const float* cb  = (const float*)d_in[17];
  float* out = (float*)d_out;

  const int n    = in_sizes[0] / 16;   // 100000
  const int ne   = in_sizes[1] / 2;    // 1600000
  const int etot = ne + n;             // + self loops

  // workspace layout
  float* A    = (float*)d_ws;                 // [n,128] layer input / residual (fp32)
  float* Bf   = A  + (size_t)n*128;           // [n,128] bf16 h slot
  unsigned short* Hb = (unsigned short*)Bf;
  float* asrc = Bf + (size_t)n*128;           // [n,4]
  float* adst = asrc + (size_t)n*4;           // [n,4]
  int* deg    = (int*)(adst + (size_t)n*4);
  int* rowst  = deg + n;                      // [n+1]
  int* cursor = rowst + n + 1;                // [n]
  int* esrc   = cursor + n;                   // [etot]
  int* blksum = esrc + etot;                  // [64]

  // ---- CSR build ----
  hipMemsetAsync(deg, 0, (size_t)n*sizeof(int), stream);
  hist_k<<<CDIV(etot,256),256,0,stream>>>(ei, deg, ne, etot);
  int nblk = CDIV(n, SCHUNK);
  scan_part_k<<<nblk,256,0,stream>>>(deg, rowst, blksum, n);
  scan_top_k<<<1,256,0,stream>>>(blksum, nblk);
  scan_add_k<<<CDIV(n,256),256,0,stream>>>(rowst, blksum, cursor, n, etot);
  for (int p = 0; p < 4; ++p){
    int lo = (int)((size_t)n * p / 4);
    int hi = (int)((size_t)n * (p+1) / 4);
    scatter_k<<<CDIV(etot,256),256,0,stream>>>(ei, cursor, esrc, ne, etot, lo, hi);
  }

  // ---- layer 1 ----  (K=16, M=128, NPT=4 -> NT=64)
  gemm_att_k<16,16,128,4,4><<<CDIV(n,64),256,0,stream>>>(x, W1, aS1, aD1, Hb, asrc, adst, n);
  agg4_k<false><<<CDIV(n,4),256,0,stream>>>(Hb, asrc, adst, rowst, esrc, b1, A, n);

  // ---- layer 2 (+residual) ----  (K=128, KC=32, M=128, NPT=4 -> NT=64)
  gemm_att_k<128,32,128,4,4><<<CDIV(n,64),256,0,stream>>>(A, W2, aS2, aD2, Hb, asrc, adst, n);
  agg4_k<true><<<CDIV(n,4),256,0,stream>>>(Hb, asrc, adst, rowst, esrc, b2, A, n);

  // ---- layer 3 (K=128, M=32, NPT=1 -> NT=64) + heads fused ----
  gemm_att_k<128,32,32,1,1><<<CDIV(n,64),256,0,stream>>>(A, W3, aS3, aD3, Hb, asrc, adst, n);
  agg1_heads_k<<<CDIV(n,4),256,0,stream>>>(Hb, asrc, adst, rowst, esrc, b3, rw, rb, cw, cb, out, n);
}